// Round 12
// baseline (736.291 us; speedup 1.0000x reference)
//
#include <hip/hip_runtime.h>
#include <hip/hip_fp16.h>

#define T_STEPS 256
#define OBS 512      // obs dim = number of independent per-row LSTMs
#define ACT 32
#define HID 1024     // output rows (hidden_dim)
#define PED 128      // pos_em_dim = LSTM hidden size
#define MSG 128      // msg_dim
#define GATES 512    // 4*PED
#define HSTR 136     // h_s row stride in halfs
#define KSTR 17      // kbuf row stride in half8 units (272B)
#define NPROD 128
#define NCONS 128
#define L1 1.4426950408889634f
#define L2C 2.8853900817779268f
// scale folded into q~ and cb: tanh(S/sqrt(128)) = 1 - 2/(exp2(QSCALE*S)+1)
#define QSCALE 0.2550348805576823f   // 2*log2(e)/sqrt(128)

typedef _Float16 half8  __attribute__((ext_vector_type(8)));
typedef float    floatx4 __attribute__((ext_vector_type(4)));

__device__ __forceinline__ float fast_exp2(float x) { return __builtin_amdgcn_exp2f(x); }
__device__ __forceinline__ float fast_rcp(float x)  { return __builtin_amdgcn_rcpf(x); }
__device__ __forceinline__ float tanh_f(float x) {
    return fmaf(-2.0f, fast_rcp(fast_exp2(2.8853900817779268f * x) + 1.0f), 1.0f);
}

// ---------------------------------------------------------------------------
// Kernel 1: xnorm[t,n]; apre in [t][p][g]; zero the 64 progress flags.
// ---------------------------------------------------------------------------
__global__ void k_pre(const float* __restrict__ obs, const float* __restrict__ act,
                      const float* __restrict__ shift, const float* __restrict__ scale,
                      const float* __restrict__ W_ih, const float* __restrict__ b_ih,
                      const float* __restrict__ b_hh,
                      float* __restrict__ xnorm, float* __restrict__ apre_p,
                      int* __restrict__ flags) {
    int t = blockIdx.x;
    int tid = threadIdx.x;
    if (t == 0 && tid < 64) flags[tid] = 0;
    __shared__ float a_s[ACT];
    if (tid < ACT) a_s[tid] = act[t * ACT + tid];
    __syncthreads();
    for (int n = tid; n < OBS; n += 256) {
        xnorm[t * OBS + n] = (obs[t * OBS + n] - shift[n]) / (scale[n] + 1e-8f);
    }
    for (int j = tid; j < GATES; j += 256) {
        float acc = b_ih[j] + b_hh[j];
        const float* wr = W_ih + j * 33 + 1;
#pragma unroll
        for (int u = 0; u < ACT; ++u) acc = fmaf(a_s[u], wr[u], acc);
        int g = j >> 7, p = j & 127;
        apre_p[t * GATES + p * 4 + g] = acc;
    }
}

// ---------------------------------------------------------------------------
// Kernel 2: q~[m] = QSCALE * Wk^T (Wq pe_m + bq)  (fp16), cb[m] = QSCALE * q·bk
// ---------------------------------------------------------------------------
__global__ void k_qproj(const float* __restrict__ pe, const float* __restrict__ Wq,
                        const float* __restrict__ bq, const float* __restrict__ Wk,
                        const float* __restrict__ bk,
                        _Float16* __restrict__ qh, float* __restrict__ cb) {
    int m = blockIdx.x;
    int d = threadIdx.x;  // 0..127
    __shared__ float pe_s[PED];
    __shared__ float q_s[PED];
    __shared__ float red_s[2];
    pe_s[d] = pe[m * PED + d];
    __syncthreads();
    const float* wr = Wq + d * PED;
    float a = bq[d];
#pragma unroll 8
    for (int p = 0; p < PED; ++p) a = fmaf(pe_s[p], wr[p], a);
    q_s[d] = a;
    float pb = a * bk[d];
#pragma unroll
    for (int off = 32; off; off >>= 1) pb += __shfl_xor(pb, off, 64);
    if ((d & 63) == 0) red_s[d >> 6] = pb;
    __syncthreads();
    float acc = 0.f;
#pragma unroll 8
    for (int p = 0; p < PED; ++p) acc = fmaf(q_s[p], Wk[p * PED + d], acc);
    qh[m * PED + d] = (_Float16)(acc * QSCALE);
    if (d == 0) cb[m] = (red_s[0] + red_s[1]) * QSCALE;
}

// ---------------------------------------------------------------------------
// Kernel 3 (fused producer/consumer):
//  blocks 0..127:   LSTM scan (R11 structure, 4 rows/block), release-signal
//                   flags[t/4] every 4 steps (one RMW, flushes L2 dirty h).
//  blocks 128..255: attention consumers; block c handles t = 2c, 2c+1.
//                   Poll = RELAXED agent fetch_add(0) (coherence-point read,
//                   NO cache invalidation — R5's poison); one ACQUIRE after
//                   success. Whole t per block -> H16[t] pulled into one XCD.
//  Dependency is one-directional: no deadlock under any scheduling; worst
//  case degrades to serial execution.
// ---------------------------------------------------------------------------
__global__ __launch_bounds__(512, 1)
void k_fused(const float* __restrict__ xnorm, const float* __restrict__ apre_p,
             const float* __restrict__ W_ih, const float* __restrict__ W_hh,
             _Float16* __restrict__ H16, int* __restrict__ flags,
             const _Float16* __restrict__ qh, const float* __restrict__ cb,
             float* __restrict__ outp) {
    __shared__ __align__(16) char smem[49152];
    const int tid = threadIdx.x;
    const int lane = tid & 63;
    const int l15 = lane & 15, quad = lane >> 4;

    if (blockIdx.x < NPROD) {
        // ===================== PRODUCER (LSTM scan) =====================
        const int wv = tid >> 6;
        const int n0 = blockIdx.x * 4;
        const int p = 16 * wv + l15;

        half8 bfr[4][4];
        float wih0[4];
#pragma unroll
        for (int g = 0; g < 4; ++g) {
            const int col = 128 * g + p;
            const float* wrow = W_hh + (size_t)col * PED;
#pragma unroll
            for (int c = 0; c < 4; ++c) {
                const int k0 = c * 32 + quad * 8;
                float4 f0 = *(const float4*)(wrow + k0);
                float4 f1 = *(const float4*)(wrow + k0 + 4);
                bfr[g][c] = (half8){(_Float16)f0.x, (_Float16)f0.y, (_Float16)f0.z, (_Float16)f0.w,
                                    (_Float16)f1.x, (_Float16)f1.y, (_Float16)f1.z, (_Float16)f1.w};
            }
            wih0[g] = W_ih[(size_t)col * 33];
        }

        _Float16* h_s = (_Float16*)smem;                  // 2 x 16*HSTR halfs
        float* x_s = (float*)(smem + 2 * 16 * HSTR * 2);  // T_STEPS*4 floats

        for (int idx = tid; idx < T_STEPS * 4; idx += 512)
            x_s[idx] = xnorm[(idx >> 2) * OBS + n0 + (idx & 3)];
        for (int idx = tid; idx < 2 * 16 * HSTR; idx += 512)
            h_s[idx] = (_Float16)0.f;

        float c0 = 0.f;
        const float* apl = apre_p + p * 4;
        float4 ap = *(const float4*)(apl);
        __syncthreads();

        _Float16* Hg = H16 + (size_t)(n0 + quad) * MSG + p;
        int buf = 0;
        for (int t = 0; t < T_STEPS; ++t) {
            half8 af[4];
            const _Float16* hb = h_s + buf * (16 * HSTR) + l15 * HSTR + quad * 8;
#pragma unroll
            for (int c = 0; c < 4; ++c) af[c] = *(const half8*)(hb + c * 32);

            floatx4 acc[4];
            acc[0] = (floatx4){ap.x, ap.x, ap.x, ap.x};
            acc[1] = (floatx4){ap.y, ap.y, ap.y, ap.y};
            acc[2] = (floatx4){ap.z, ap.z, ap.z, ap.z};
            acc[3] = (floatx4){ap.w, ap.w, ap.w, ap.w};
#pragma unroll
            for (int g = 0; g < 4; ++g)
#pragma unroll
                for (int c = 0; c < 4; ++c)
                    acc[g] = __builtin_amdgcn_mfma_f32_16x16x32_f16(
                        af[c], bfr[g][c], acc[g], 0, 0, 0);

            const int tn = (t + 1 < T_STEPS) ? t + 1 : t;
            float4 ap_n = *(const float4*)(apl + tn * GATES);

            const float x = x_s[t * 4 + quad];
            float gi = fmaf(x, wih0[0], acc[0][0]);
            float gf = fmaf(x, wih0[1], acc[1][0]);
            float gg = fmaf(x, wih0[2], acc[2][0]);
            float go = fmaf(x, wih0[3], acc[3][0]);

            float Di = 1.f + fast_exp2(fminf(-L1 * gi, 20.f));
            float Df = 1.f + fast_exp2(fminf(-L1 * gf, 20.f));
            float Dg = 1.f + fast_exp2(fminf(L2C * gg, 20.f));
            float DfDg = Df * Dg, DiDg = Di * Dg, DiDf = Di * Df;
            float r3 = fast_rcp(Di * DfDg);
            float iDi = r3 * DfDg, iDf = r3 * DiDg, iDg = r3 * DiDf;
            float cn = fmaf(iDf, c0, iDi * fmaf(-2.f, iDg, 1.f));
            c0 = cn;
            float Do = 1.f + fast_exp2(fminf(-L1 * go, 20.f));
            float Dc = 1.f + fast_exp2(fminf(L2C * cn, 20.f));
            float r2 = fast_rcp(Do * Dc);
            float iDo = r2 * Dc, iDc = r2 * Do;
            _Float16 hq = (_Float16)(iDo * fmaf(-2.f, iDc, 1.f));

            h_s[(buf ^ 1) * (16 * HSTR) + (4 * quad) * HSTR + p] = hq;
            Hg[0] = hq;
            Hg += OBS * MSG;

            ap = ap_n;
            buf ^= 1;
            __syncthreads();   // compiler emits vmcnt(0) before this: H16 stores complete

            if ((t & 3) == 3 && tid == 0)
                __hip_atomic_fetch_add(&flags[t >> 2], 1, __ATOMIC_RELEASE,
                                       __HIP_MEMORY_SCOPE_AGENT);
        }
    } else {
        // ===================== CONSUMER (attention) =====================
        const int cidx = blockIdx.x - NPROD;          // 0..127
        const int wave = tid >> 6;                    // 8 waves
        half8* kbuf = (half8*)smem;                   // 2 x 64*KSTR half8 = 34816B

        for (int pass = 0; pass < 2; ++pass) {
            const int t = cidx * 2 + pass;

            if (tid == 0) {
                int it = 0;
                while (__hip_atomic_fetch_add(&flags[t >> 2], 0, __ATOMIC_RELAXED,
                                              __HIP_MEMORY_SCOPE_AGENT) < NPROD) {
                    __builtin_amdgcn_s_sleep(32);
                    if (++it > (1 << 22)) break;      // hang-preventer only
                }
                // single acquire: invalidate caches once, then read H16[t]
                __hip_atomic_fetch_add(&flags[t >> 2], 0, __ATOMIC_ACQUIRE,
                                       __HIP_MEMORY_SCOPE_AGENT);
            }
            __syncthreads();

            const half8* Ht = (const half8*)(H16 + (size_t)t * (OBS * MSG));
            const float* xb = xnorm + t * OBS;

            for (int mq = 0; mq < 4; ++mq) {
                const int m0 = mq * 256 + wave * 32;

                half8 afrag[2][4];
                floatx4 cbv[2];
#pragma unroll
                for (int mt = 0; mt < 2; ++mt) {
                    const half8* qrow = (const half8*)(qh + (size_t)(m0 + mt * 16 + l15) * PED);
#pragma unroll
                    for (int c = 0; c < 4; ++c) afrag[mt][c] = qrow[c * 4 + quad];
                    cbv[mt] = *(const floatx4*)(cb + m0 + mt * 16 + quad * 4);
                }

                float outacc[8];
#pragma unroll
                for (int i = 0; i < 8; ++i) outacc[i] = 0.f;

                // stage chunk 0 (1024 half8 over 512 threads)
                half8 pf[2];
#pragma unroll
                for (int i = 0; i < 2; ++i) pf[i] = Ht[i * 512 + tid];
#pragma unroll
                for (int i = 0; i < 2; ++i) {
                    int f = i * 512 + tid;
                    kbuf[(f >> 4) * KSTR + (f & 15)] = pf[i];
                }
                __syncthreads();

                for (int ch = 0; ch < 8; ++ch) {
                    const int cur = ch & 1;
                    if (ch < 7) {
                        const half8* Hn = Ht + (ch + 1) * 1024;
#pragma unroll
                        for (int i = 0; i < 2; ++i) pf[i] = Hn[i * 512 + tid];
                    }

#pragma unroll
                    for (int nt = 0; nt < 4; ++nt) {
                        half8 bfrag[4];
#pragma unroll
                        for (int c = 0; c < 4; ++c)
                            bfrag[c] = kbuf[cur * (64 * KSTR) + (nt * 16 + l15) * KSTR + c * 4 + quad];

                        floatx4 acc[2];
#pragma unroll
                        for (int mt = 0; mt < 2; ++mt) {
                            acc[mt] = cbv[mt];
#pragma unroll
                            for (int c = 0; c < 4; ++c)
                                acc[mt] = __builtin_amdgcn_mfma_f32_16x16x32_f16(
                                    afrag[mt][c], bfrag[c], acc[mt], 0, 0, 0);
                        }

                        const float sv = xb[ch * 64 + nt * 16 + l15];
#pragma unroll
                        for (int mt = 0; mt < 2; ++mt) {
                            float E0 = fast_exp2(fminf(acc[mt][0], 20.f));
                            float E1 = fast_exp2(fminf(acc[mt][1], 20.f));
                            float E2 = fast_exp2(fminf(acc[mt][2], 20.f));
                            float E3 = fast_exp2(fminf(acc[mt][3], 20.f));
                            float D0 = 1.f + E0, D1 = 1.f + E1, D2 = 1.f + E2, D3 = 1.f + E3;
                            float m01 = D0 * D1, m23 = D2 * D3;
                            float rp = fast_rcp(m01 * m23);
                            float rA = rp * m23, rB = rp * m01;
                            float i0 = rA * D1, i1 = rA * D0, i2 = rB * D3, i3 = rB * D2;
                            outacc[mt * 4 + 0] = fmaf(fmaf(-2.f, i0, 1.f), sv, outacc[mt * 4 + 0]);
                            outacc[mt * 4 + 1] = fmaf(fmaf(-2.f, i1, 1.f), sv, outacc[mt * 4 + 1]);
                            outacc[mt * 4 + 2] = fmaf(fmaf(-2.f, i2, 1.f), sv, outacc[mt * 4 + 2]);
                            outacc[mt * 4 + 3] = fmaf(fmaf(-2.f, i3, 1.f), sv, outacc[mt * 4 + 3]);
                        }
                    }

                    if (ch < 7) {
#pragma unroll
                        for (int i = 0; i < 2; ++i) {
                            int f = i * 512 + tid;
                            kbuf[(cur ^ 1) * (64 * KSTR) + (f >> 4) * KSTR + (f & 15)] = pf[i];
                        }
                    }
                    __syncthreads();
                }

#pragma unroll
                for (int i = 0; i < 8; ++i) {
                    float v = outacc[i];
                    v += __shfl_xor(v, 1, 16);
                    v += __shfl_xor(v, 2, 16);
                    v += __shfl_xor(v, 4, 16);
                    v += __shfl_xor(v, 8, 16);
                    outacc[i] = v;
                }
                if (l15 == 0) {
                    const int mbase = m0 + quad * 4;
#pragma unroll
                    for (int mt = 0; mt < 2; ++mt)
#pragma unroll
                        for (int r = 0; r < 4; ++r)
                            outp[(size_t)t * HID + mbase + mt * 16 + r] =
                                tanh_f(outacc[mt * 4 + r]);
                }
                __syncthreads();
            }
        }
    }
}

// ---------------------------------------------------------------------------
extern "C" void kernel_launch(void* const* d_in, const int* in_sizes, int n_in,
                              void* d_out, int out_size, void* d_ws, size_t ws_size,
                              hipStream_t stream) {
    const float* obs      = (const float*)d_in[0];   // (256,512)
    const float* prev_act = (const float*)d_in[1];   // (256,32)
    const float* in_shift = (const float*)d_in[2];   // (512,)
    const float* in_scale = (const float*)d_in[3];   // (512,)
    const float* pos_emb  = (const float*)d_in[4];   // (1024,128)
    const float* W_ih     = (const float*)d_in[5];   // (512,33)
    const float* b_ih     = (const float*)d_in[6];   // (512,)
    const float* W_hh     = (const float*)d_in[7];   // (512,128)
    const float* b_hh     = (const float*)d_in[8];   // (512,)
    const float* Wq       = (const float*)d_in[9];   // (128,128)
    const float* bq       = (const float*)d_in[10];  // (128,)
    const float* Wk       = (const float*)d_in[11];  // (128,128)
    const float* bk       = (const float*)d_in[12];  // (128,)
    float* outp = (float*)d_out;                     // (256,1024)

    // workspace layout (float offsets):
    //   xnorm:  0        (131072 f)
    //   apre_p: 131072   (131072 f)
    //   qh:     262144   (131072 halfs = 65536 f)
    //   cb:     327680   (1024 f)
    //   flags:  328704   (64 int)
    //   H16:    328768   (16777216 halfs)
    float* ws = (float*)d_ws;
    float* xnorm  = ws;
    float* apre_p = ws + 131072;
    _Float16* qh  = (_Float16*)(ws + 262144);
    float* cbuf   = ws + 327680;
    int* flags    = (int*)(ws + 328704);
    _Float16* H16 = (_Float16*)(ws + 328768);

    k_pre<<<T_STEPS, 256, 0, stream>>>(obs, prev_act, in_shift, in_scale,
                                       W_ih, b_ih, b_hh, xnorm, apre_p, flags);
    k_qproj<<<HID, 128, 0, stream>>>(pos_emb, Wq, bq, Wk, bk, qh, cbuf);
    k_fused<<<NPROD + NCONS, 512, 0, stream>>>(xnorm, apre_p, W_ih, W_hh,
                                               H16, flags, qh, cbuf, outp);
}

// Round 13
// 395.465 us; speedup vs baseline: 1.8618x; 1.8618x over previous
//
#include <hip/hip_runtime.h>
#include <hip/hip_fp16.h>

#define T_STEPS 256
#define OBS 512
#define ACT 32
#define HID 1024
#define PED 128
#define MSG 128
#define GATES 512
#define HSTR 136     // h_s row stride in halfs
#define KSTR 17      // kbuf row stride in half8 units (272B)
#define NPROD 128
#define NBLK 256
#define L1 1.4426950408889634f
#define L2C 2.8853900817779268f
#define QSCALE 0.2550348805576823f   // 2*log2(e)/sqrt(128)

typedef _Float16 half8  __attribute__((ext_vector_type(8)));
typedef float    floatx4 __attribute__((ext_vector_type(4)));

__device__ __forceinline__ float fast_exp2(float x) { return __builtin_amdgcn_exp2f(x); }
__device__ __forceinline__ float fast_rcp(float x)  { return __builtin_amdgcn_rcpf(x); }
__device__ __forceinline__ float tanh_f(float x) {
    return fmaf(-2.0f, fast_rcp(fast_exp2(2.8853900817779268f * x) + 1.0f), 1.0f);
}

// flags layout (ints): [0..8191] per-(group,producer) ready slots;
// [8192] acquire dummy; [8193] work-queue head.
#define FLG_N 8194

// ---------------------------------------------------------------------------
// Kernel 1: xnorm, apre permute, zero flags/queue.
// ---------------------------------------------------------------------------
__global__ void k_pre(const float* __restrict__ obs, const float* __restrict__ act,
                      const float* __restrict__ shift, const float* __restrict__ scale,
                      const float* __restrict__ W_ih, const float* __restrict__ b_ih,
                      const float* __restrict__ b_hh,
                      float* __restrict__ xnorm, float* __restrict__ apre_p,
                      int* __restrict__ flags) {
    int t = blockIdx.x;
    int tid = threadIdx.x;
    int zi = t * 256 + tid;
    if (zi < FLG_N) flags[zi] = 0;
    __shared__ float a_s[ACT];
    if (tid < ACT) a_s[tid] = act[t * ACT + tid];
    __syncthreads();
    for (int n = tid; n < OBS; n += 256) {
        xnorm[t * OBS + n] = (obs[t * OBS + n] - shift[n]) / (scale[n] + 1e-8f);
    }
    for (int j = tid; j < GATES; j += 256) {
        float acc = b_ih[j] + b_hh[j];
        const float* wr = W_ih + j * 33 + 1;
#pragma unroll
        for (int u = 0; u < ACT; ++u) acc = fmaf(a_s[u], wr[u], acc);
        int g = j >> 7, p = j & 127;
        apre_p[t * GATES + p * 4 + g] = acc;
    }
}

// ---------------------------------------------------------------------------
// Kernel 2: q~[m] = QSCALE * Wk^T (Wq pe_m + bq) (fp16), cb[m] = QSCALE * q·bk
// ---------------------------------------------------------------------------
__global__ void k_qproj(const float* __restrict__ pe, const float* __restrict__ Wq,
                        const float* __restrict__ bq, const float* __restrict__ Wk,
                        const float* __restrict__ bk,
                        _Float16* __restrict__ qh, float* __restrict__ cb) {
    int m = blockIdx.x;
    int d = threadIdx.x;  // 0..127
    __shared__ float pe_s[PED];
    __shared__ float q_s[PED];
    __shared__ float red_s[2];
    pe_s[d] = pe[m * PED + d];
    __syncthreads();
    const float* wr = Wq + d * PED;
    float a = bq[d];
#pragma unroll 8
    for (int p = 0; p < PED; ++p) a = fmaf(pe_s[p], wr[p], a);
    q_s[d] = a;
    float pb = a * bk[d];
#pragma unroll
    for (int off = 32; off; off >>= 1) pb += __shfl_xor(pb, off, 64);
    if ((d & 63) == 0) red_s[d >> 6] = pb;
    __syncthreads();
    float acc = 0.f;
#pragma unroll 8
    for (int p = 0; p < PED; ++p) acc = fmaf(q_s[p], Wk[p * PED + d], acc);
    qh[m * PED + d] = (_Float16)(acc * QSCALE);
    if (d == 0) cb[m] = (red_s[0] + red_s[1]) * QSCALE;
}

// ---------------------------------------------------------------------------
// attention consumer for one (t, mq) item — 512 threads, 8 waves, 2 m-tiles.
// ---------------------------------------------------------------------------
__device__ __forceinline__ void attn_item(
        int t, int mq, char* smem,
        const _Float16* __restrict__ qh, const float* __restrict__ cb,
        const _Float16* __restrict__ H16, const float* __restrict__ xnorm,
        float* __restrict__ outp) {
    const int tid = threadIdx.x;
    const int lane = tid & 63, wave = tid >> 6;
    const int l15 = lane & 15, quad = lane >> 4;
    half8* kbuf = (half8*)smem;                   // 2 x 64*KSTR half8

    const int m0 = mq * 256 + wave * 32;
    half8 afrag[2][4];
    floatx4 cbv[2];
#pragma unroll
    for (int mt = 0; mt < 2; ++mt) {
        const half8* qrow = (const half8*)(qh + (size_t)(m0 + mt * 16 + l15) * PED);
#pragma unroll
        for (int c = 0; c < 4; ++c) afrag[mt][c] = qrow[c * 4 + quad];
        cbv[mt] = *(const floatx4*)(cb + m0 + mt * 16 + quad * 4);
    }

    float outacc[8];
#pragma unroll
    for (int i = 0; i < 8; ++i) outacc[i] = 0.f;

    const half8* Ht = (const half8*)(H16 + (size_t)t * (OBS * MSG));
    const float* xb = xnorm + t * OBS;

    half8 pf[2];
#pragma unroll
    for (int i = 0; i < 2; ++i) pf[i] = Ht[i * 512 + tid];
#pragma unroll
    for (int i = 0; i < 2; ++i) {
        int f = i * 512 + tid;
        kbuf[(f >> 4) * KSTR + (f & 15)] = pf[i];
    }
    __syncthreads();

    for (int ch = 0; ch < 8; ++ch) {
        const int cur = ch & 1;
        if (ch < 7) {
            const half8* Hn = Ht + (ch + 1) * 1024;
#pragma unroll
            for (int i = 0; i < 2; ++i) pf[i] = Hn[i * 512 + tid];
        }

#pragma unroll
        for (int nt = 0; nt < 4; ++nt) {
            half8 bfrag[4];
#pragma unroll
            for (int c = 0; c < 4; ++c)
                bfrag[c] = kbuf[cur * (64 * KSTR) + (nt * 16 + l15) * KSTR + c * 4 + quad];

            floatx4 acc[2];
#pragma unroll
            for (int mt = 0; mt < 2; ++mt) {
                acc[mt] = cbv[mt];
#pragma unroll
                for (int c = 0; c < 4; ++c)
                    acc[mt] = __builtin_amdgcn_mfma_f32_16x16x32_f16(
                        afrag[mt][c], bfrag[c], acc[mt], 0, 0, 0);
            }

            const float sv = xb[ch * 64 + nt * 16 + l15];
#pragma unroll
            for (int mt = 0; mt < 2; ++mt) {
                float E0 = fast_exp2(fminf(acc[mt][0], 20.f));
                float E1 = fast_exp2(fminf(acc[mt][1], 20.f));
                float E2 = fast_exp2(fminf(acc[mt][2], 20.f));
                float E3 = fast_exp2(fminf(acc[mt][3], 20.f));
                float D0 = 1.f + E0, D1 = 1.f + E1, D2 = 1.f + E2, D3 = 1.f + E3;
                float m01 = D0 * D1, m23 = D2 * D3;
                float rp = fast_rcp(m01 * m23);
                float rA = rp * m23, rB = rp * m01;
                float i0 = rA * D1, i1 = rA * D0, i2 = rB * D3, i3 = rB * D2;
                outacc[mt * 4 + 0] = fmaf(fmaf(-2.f, i0, 1.f), sv, outacc[mt * 4 + 0]);
                outacc[mt * 4 + 1] = fmaf(fmaf(-2.f, i1, 1.f), sv, outacc[mt * 4 + 1]);
                outacc[mt * 4 + 2] = fmaf(fmaf(-2.f, i2, 1.f), sv, outacc[mt * 4 + 2]);
                outacc[mt * 4 + 3] = fmaf(fmaf(-2.f, i3, 1.f), sv, outacc[mt * 4 + 3]);
            }
        }

        if (ch < 7) {
#pragma unroll
            for (int i = 0; i < 2; ++i) {
                int f = i * 512 + tid;
                kbuf[(cur ^ 1) * (64 * KSTR) + (f >> 4) * KSTR + (f & 15)] = pf[i];
            }
        }
        __syncthreads();
    }

#pragma unroll
    for (int i = 0; i < 8; ++i) {
        float v = outacc[i];
        v += __shfl_xor(v, 1, 16);
        v += __shfl_xor(v, 2, 16);
        v += __shfl_xor(v, 4, 16);
        v += __shfl_xor(v, 8, 16);
        outacc[i] = v;
    }
    if (l15 == 0) {
        const int mbase = m0 + quad * 4;
#pragma unroll
        for (int mt = 0; mt < 2; ++mt)
#pragma unroll
            for (int r = 0; r < 4; ++r)
                outp[(size_t)t * HID + mbase + mt * 16 + r] = tanh_f(outacc[mt * 4 + r]);
    }
    __syncthreads();
}

// ---------------------------------------------------------------------------
// Kernel 3 (fused, convoy-free sync):
//  blocks 0..127: LSTM scan (R11 structure); per-producer release STORE to
//    flags[(t/4)*128 + bid] every 4 steps (no RMW -> no convoy). After the
//    scan, role-switch into the consumer work queue.
//  blocks 128..255: consumers from the start. Items = (t, mq), popped from a
//    single low-rate atomic head. Readiness poll = lane-parallel RELAXED
//    atomic LOADS + __syncthreads_and (no RMW, no invalidate), then ONE
//    acquire RMW on a dummy line. s_sleep while waiting (no issue pressure).
// ---------------------------------------------------------------------------
__global__ __launch_bounds__(512, 1)
void k_fused(const float* __restrict__ xnorm, const float* __restrict__ apre_p,
             const float* __restrict__ W_ih, const float* __restrict__ W_hh,
             _Float16* __restrict__ H16, int* __restrict__ flags,
             const _Float16* __restrict__ qh, const float* __restrict__ cb,
             float* __restrict__ outp) {
    __shared__ __align__(16) char smem[34816];
    const int tid = threadIdx.x;
    const int lane = tid & 63;
    const int l15 = lane & 15, quad = lane >> 4;
    int* qhead = &flags[8193];

    if (blockIdx.x < NPROD) {
        // ===================== PRODUCER (LSTM scan, R11) =====================
        const int wv = tid >> 6;
        const int n0 = blockIdx.x * 4;
        const int p = 16 * wv + l15;

        half8 bfr[4][4];
        float wih0[4];
#pragma unroll
        for (int g = 0; g < 4; ++g) {
            const int col = 128 * g + p;
            const float* wrow = W_hh + (size_t)col * PED;
#pragma unroll
            for (int c = 0; c < 4; ++c) {
                const int k0 = c * 32 + quad * 8;
                float4 f0 = *(const float4*)(wrow + k0);
                float4 f1 = *(const float4*)(wrow + k0 + 4);
                bfr[g][c] = (half8){(_Float16)f0.x, (_Float16)f0.y, (_Float16)f0.z, (_Float16)f0.w,
                                    (_Float16)f1.x, (_Float16)f1.y, (_Float16)f1.z, (_Float16)f1.w};
            }
            wih0[g] = W_ih[(size_t)col * 33];
        }

        _Float16* h_s = (_Float16*)smem;                  // 2 x 16*HSTR halfs
        float* x_s = (float*)(smem + 2 * 16 * HSTR * 2);  // 4 KB

        for (int idx = tid; idx < T_STEPS * 4; idx += 512)
            x_s[idx] = xnorm[(idx >> 2) * OBS + n0 + (idx & 3)];
        for (int idx = tid; idx < 2 * 16 * HSTR; idx += 512)
            h_s[idx] = (_Float16)0.f;

        float c0 = 0.f;
        const float* apl = apre_p + p * 4;
        float4 ap = *(const float4*)(apl);
        __syncthreads();

        _Float16* Hg = H16 + (size_t)(n0 + quad) * MSG + p;
        int buf = 0;
        for (int t = 0; t < T_STEPS; ++t) {
            half8 af[4];
            const _Float16* hb = h_s + buf * (16 * HSTR) + l15 * HSTR + quad * 8;
#pragma unroll
            for (int c = 0; c < 4; ++c) af[c] = *(const half8*)(hb + c * 32);

            floatx4 acc[4];
            acc[0] = (floatx4){ap.x, ap.x, ap.x, ap.x};
            acc[1] = (floatx4){ap.y, ap.y, ap.y, ap.y};
            acc[2] = (floatx4){ap.z, ap.z, ap.z, ap.z};
            acc[3] = (floatx4){ap.w, ap.w, ap.w, ap.w};
#pragma unroll
            for (int g = 0; g < 4; ++g)
#pragma unroll
                for (int c = 0; c < 4; ++c)
                    acc[g] = __builtin_amdgcn_mfma_f32_16x16x32_f16(
                        af[c], bfr[g][c], acc[g], 0, 0, 0);

            const int tn = (t + 1 < T_STEPS) ? t + 1 : t;
            float4 ap_n = *(const float4*)(apl + tn * GATES);

            const float x = x_s[t * 4 + quad];
            float gi = fmaf(x, wih0[0], acc[0][0]);
            float gf = fmaf(x, wih0[1], acc[1][0]);
            float gg = fmaf(x, wih0[2], acc[2][0]);
            float go = fmaf(x, wih0[3], acc[3][0]);

            float Di = 1.f + fast_exp2(fminf(-L1 * gi, 20.f));
            float Df = 1.f + fast_exp2(fminf(-L1 * gf, 20.f));
            float Dg = 1.f + fast_exp2(fminf(L2C * gg, 20.f));
            float DfDg = Df * Dg, DiDg = Di * Dg, DiDf = Di * Df;
            float r3 = fast_rcp(Di * DfDg);
            float iDi = r3 * DfDg, iDf = r3 * DiDg, iDg = r3 * DiDf;
            float cn = fmaf(iDf, c0, iDi * fmaf(-2.f, iDg, 1.f));
            c0 = cn;
            float Do = 1.f + fast_exp2(fminf(-L1 * go, 20.f));
            float Dc = 1.f + fast_exp2(fminf(L2C * cn, 20.f));
            float r2 = fast_rcp(Do * Dc);
            float iDo = r2 * Dc, iDc = r2 * Do;
            _Float16 hq = (_Float16)(iDo * fmaf(-2.f, iDc, 1.f));

            h_s[(buf ^ 1) * (16 * HSTR) + (4 * quad) * HSTR + p] = hq;
            Hg[0] = hq;
            Hg += OBS * MSG;

            ap = ap_n;
            buf ^= 1;
            __syncthreads();   // vmcnt(0) drain: this step's H16 stores complete

            if ((t & 3) == 3 && tid == 0)
                __hip_atomic_store(&flags[(t >> 2) * 128 + blockIdx.x], 1,
                                   __ATOMIC_RELEASE, __HIP_MEMORY_SCOPE_AGENT);
        }
        __syncthreads();
        // fall through to consumer role
    }

    // ===================== CONSUMER (work queue) =====================
    __shared__ int item_s;
    for (;;) {
        if (tid == 0)
            item_s = __hip_atomic_fetch_add(qhead, 1, __ATOMIC_RELAXED,
                                            __HIP_MEMORY_SCOPE_AGENT);
        __syncthreads();
        const int item = item_s;
        __syncthreads();
        if (item >= 1024) break;
        const int t = item >> 2, mq = item & 3;

        // readiness poll: relaxed loads only, reduce via syncthreads_and
        const int gbase = (t >> 2) * 128;
        for (int it = 0; ; ++it) {
            int ok = 1;
            if (tid < 128)
                ok = (__hip_atomic_load(&flags[gbase + tid], __ATOMIC_RELAXED,
                                        __HIP_MEMORY_SCOPE_AGENT) != 0);
            if (__syncthreads_and(ok)) break;
            if (it > (1 << 20)) break;            // hang-preventer only
            __builtin_amdgcn_s_sleep(16);
        }
        if (tid == 0)
            __hip_atomic_fetch_add(&flags[8192], 0, __ATOMIC_ACQUIRE,
                                   __HIP_MEMORY_SCOPE_AGENT);
        __syncthreads();

        attn_item(t, mq, smem, qh, cb, H16, xnorm, outp);
    }
}

// ---------------------------------------------------------------------------
extern "C" void kernel_launch(void* const* d_in, const int* in_sizes, int n_in,
                              void* d_out, int out_size, void* d_ws, size_t ws_size,
                              hipStream_t stream) {
    const float* obs      = (const float*)d_in[0];   // (256,512)
    const float* prev_act = (const float*)d_in[1];   // (256,32)
    const float* in_shift = (const float*)d_in[2];   // (512,)
    const float* in_scale = (const float*)d_in[3];   // (512,)
    const float* pos_emb  = (const float*)d_in[4];   // (1024,128)
    const float* W_ih     = (const float*)d_in[5];   // (512,33)
    const float* b_ih     = (const float*)d_in[6];   // (512,)
    const float* W_hh     = (const float*)d_in[7];   // (512,128)
    const float* b_hh     = (const float*)d_in[8];   // (512,)
    const float* Wq       = (const float*)d_in[9];   // (128,128)
    const float* bq       = (const float*)d_in[10];  // (128,)
    const float* Wk       = (const float*)d_in[11];  // (128,128)
    const float* bk       = (const float*)d_in[12];  // (128,)
    float* outp = (float*)d_out;                     // (256,1024)

    // workspace (float offsets):
    //   xnorm 0, apre 131072, qh 262144 (32768f), cb 327680 (1024f),
    //   flags 328704 (8194 ints -> 8208f pad), H16 336912
    float* ws = (float*)d_ws;
    float* xnorm  = ws;
    float* apre_p = ws + 131072;
    _Float16* qh  = (_Float16*)(ws + 262144);
    float* cbuf   = ws + 327680;
    int* flags    = (int*)(ws + 328704);
    _Float16* H16 = (_Float16*)(ws + 336912);

    k_pre<<<T_STEPS, 256, 0, stream>>>(obs, prev_act, in_shift, in_scale,
                                       W_ih, b_ih, b_hh, xnorm, apre_p, flags);
    k_qproj<<<HID, 128, 0, stream>>>(pos_emb, Wq, bq, Wk, bk, qh, cbuf);
    k_fused<<<NBLK, 512, 0, stream>>>(xnorm, apre_p, W_ih, W_hh,
                                      H16, flags, qh, cbuf, outp);
}

// Round 14
// 315.177 us; speedup vs baseline: 2.3361x; 1.2547x over previous
//
#include <hip/hip_runtime.h>
#include <hip/hip_fp16.h>

#define T_STEPS 256
#define OBS 512      // obs dim = number of independent per-row LSTMs
#define ACT 32
#define HID 1024     // output rows (hidden_dim)
#define PED 128      // pos_em_dim = LSTM hidden size
#define MSG 128      // msg_dim
#define GATES 512    // 4*PED
#define HSTR 136     // h_s row stride in halfs
#define KSTR 17      // kbuf row stride in half8 units (272B)
#define L1 1.4426950408889634f
#define L2C 2.8853900817779268f
// scale folded into q~ and cb: tanh(S/sqrt(128)) = 1 - 2/(exp2(QSCALE*S)+1)
#define QSCALE 0.2550348805576823f   // 2*log2(e)/sqrt(128)

typedef _Float16 half8  __attribute__((ext_vector_type(8)));
typedef float    floatx4 __attribute__((ext_vector_type(4)));

__device__ __forceinline__ float fast_exp2(float x) { return __builtin_amdgcn_exp2f(x); }
__device__ __forceinline__ float fast_rcp(float x)  { return __builtin_amdgcn_rcpf(x); }
__device__ __forceinline__ float tanh_f(float x) {
    return fmaf(-2.0f, fast_rcp(fast_exp2(2.8853900817779268f * x) + 1.0f), 1.0f);
}

// ---------------------------------------------------------------------------
// Kernel 1: xnorm[t,n]; apre in [t][p][g] layout:
//   apre_p[t*512 + p*4 + g] = b_ih[j]+b_hh[j]+act[t]·W_ih[j,1:],  j = 128g+p
// ---------------------------------------------------------------------------
__global__ void k_pre(const float* __restrict__ obs, const float* __restrict__ act,
                      const float* __restrict__ shift, const float* __restrict__ scale,
                      const float* __restrict__ W_ih, const float* __restrict__ b_ih,
                      const float* __restrict__ b_hh,
                      float* __restrict__ xnorm, float* __restrict__ apre_p) {
    int t = blockIdx.x;
    int tid = threadIdx.x;
    __shared__ float a_s[ACT];
    if (tid < ACT) a_s[tid] = act[t * ACT + tid];
    __syncthreads();
    for (int n = tid; n < OBS; n += 256) {
        xnorm[t * OBS + n] = (obs[t * OBS + n] - shift[n]) / (scale[n] + 1e-8f);
    }
    for (int j = tid; j < GATES; j += 256) {
        float acc = b_ih[j] + b_hh[j];
        const float* wr = W_ih + j * 33 + 1;
#pragma unroll
        for (int u = 0; u < ACT; ++u) acc = fmaf(a_s[u], wr[u], acc);
        int g = j >> 7, p = j & 127;
        apre_p[t * GATES + p * 4 + g] = acc;
    }
}

// ---------------------------------------------------------------------------
// Kernel 2: q~[m] = QSCALE * Wk^T (Wq pe_m + bq)  (fp16), cb[m] = QSCALE * q·bk
// ---------------------------------------------------------------------------
__global__ void k_qproj(const float* __restrict__ pe, const float* __restrict__ Wq,
                        const float* __restrict__ bq, const float* __restrict__ Wk,
                        const float* __restrict__ bk,
                        _Float16* __restrict__ qh, float* __restrict__ cb) {
    int m = blockIdx.x;
    int d = threadIdx.x;  // 0..127
    __shared__ float pe_s[PED];
    __shared__ float q_s[PED];
    __shared__ float red_s[2];
    pe_s[d] = pe[m * PED + d];
    __syncthreads();
    const float* wr = Wq + d * PED;
    float a = bq[d];
#pragma unroll 8
    for (int p = 0; p < PED; ++p) a = fmaf(pe_s[p], wr[p], a);
    q_s[d] = a;
    float pb = a * bk[d];
#pragma unroll
    for (int off = 32; off; off >>= 1) pb += __shfl_xor(pb, off, 64);
    if ((d & 63) == 0) red_s[d >> 6] = pb;
    __syncthreads();
    float acc = 0.f;
#pragma unroll 8
    for (int p = 0; p < PED; ++p) acc = fmaf(q_s[p], Wk[p * PED + d], acc);
    qh[m * PED + d] = (_Float16)(acc * QSCALE);
    if (d == 0) cb[m] = (red_s[0] + red_s[1]) * QSCALE;
}

// ---------------------------------------------------------------------------
// Kernel 3: LSTM scan via MFMA (R11 structure) with ONE change: the global
// H16 store is issued AFTER the step barrier (from the register), so the
// vmcnt(0) drain the compiler emits before each s_barrier finds a store
// that was issued a full step (~1000 cyc) earlier instead of ~20 instrs
// earlier. Removes the per-step store round-trip from the critical path.
// ---------------------------------------------------------------------------
__global__ __launch_bounds__(512, 1)
void k_lstm(const float* __restrict__ xnorm, const float* __restrict__ apre_p,
            const float* __restrict__ W_ih, const float* __restrict__ W_hh,
            _Float16* __restrict__ H16) {
    const int tid = threadIdx.x;
    const int lane = tid & 63, wv = tid >> 6;     // 8 waves
    const int l15 = lane & 15, quad = lane >> 4;
    const int n0 = blockIdx.x * 4;
    const int p = 16 * wv + l15;                  // gate/h unit this lane owns

    // ---- stationary B-fragments: B[n=col][k] = W_hh[col][k], col = 128g+p
    half8 bfr[4][4];
    float wih0[4];
#pragma unroll
    for (int g = 0; g < 4; ++g) {
        const int col = 128 * g + p;
        const float* wrow = W_hh + (size_t)col * PED;
#pragma unroll
        for (int c = 0; c < 4; ++c) {
            const int k0 = c * 32 + quad * 8;
            float4 f0 = *(const float4*)(wrow + k0);
            float4 f1 = *(const float4*)(wrow + k0 + 4);
            bfr[g][c] = (half8){(_Float16)f0.x, (_Float16)f0.y, (_Float16)f0.z, (_Float16)f0.w,
                                (_Float16)f1.x, (_Float16)f1.y, (_Float16)f1.z, (_Float16)f1.w};
        }
        wih0[g] = W_ih[(size_t)col * 33];
    }

    __shared__ _Float16 h_s[2][16 * HSTR];        // A-rows 4j hold h, rest zero
    __shared__ float x_s[T_STEPS * 4];            // 4 KB

    for (int idx = tid; idx < T_STEPS * 4; idx += 512)
        x_s[idx] = xnorm[(idx >> 2) * OBS + n0 + (idx & 3)];
    for (int idx = tid; idx < 2 * 16 * HSTR; idx += 512)
        ((_Float16*)h_s)[idx] = (_Float16)0.f;

    float c0 = 0.f;
    const float* apl = apre_p + p * 4;
    float4 ap = *(const float4*)(apl);            // (gi,gf,gg,go) pre-adds for t=0
    __syncthreads();

    _Float16* Hg = H16 + (size_t)(n0 + quad) * MSG + p;
    int buf = 0;
    for (int t = 0; t < T_STEPS; ++t) {
        // ---- A-fragments: A[m=l15][k] from h_s (b128, conflict-free)
        half8 af[4];
        const _Float16* hb = h_s[buf] + l15 * HSTR + quad * 8;
#pragma unroll
        for (int c = 0; c < 4; ++c) af[c] = *(const half8*)(hb + c * 32);

        // ---- gates via MFMA, apre folded into acc init
        floatx4 acc[4];
        acc[0] = (floatx4){ap.x, ap.x, ap.x, ap.x};
        acc[1] = (floatx4){ap.y, ap.y, ap.y, ap.y};
        acc[2] = (floatx4){ap.z, ap.z, ap.z, ap.z};
        acc[3] = (floatx4){ap.w, ap.w, ap.w, ap.w};
#pragma unroll
        for (int g = 0; g < 4; ++g)
#pragma unroll
            for (int c = 0; c < 4; ++c)
                acc[g] = __builtin_amdgcn_mfma_f32_16x16x32_f16(
                    af[c], bfr[g][c], acc[g], 0, 0, 0);

        // ---- prefetch apre for t+1 (off critical path)
        const int tn = (t + 1 < T_STEPS) ? t + 1 : t;
        float4 ap_n = *(const float4*)(apl + tn * GATES);

        // ---- this lane's single cell: obs-row quad, unit p (C row 4*quad)
        const float x = x_s[t * 4 + quad];
        float gi = fmaf(x, wih0[0], acc[0][0]);
        float gf = fmaf(x, wih0[1], acc[1][0]);
        float gg = fmaf(x, wih0[2], acc[2][0]);
        float go = fmaf(x, wih0[3], acc[3][0]);

        // batched-rcp: 3 denominators, 1 rcp
        float Di = 1.f + fast_exp2(fminf(-L1 * gi, 20.f));
        float Df = 1.f + fast_exp2(fminf(-L1 * gf, 20.f));
        float Dg = 1.f + fast_exp2(fminf(L2C * gg, 20.f));
        float DfDg = Df * Dg, DiDg = Di * Dg, DiDf = Di * Df;
        float r3 = fast_rcp(Di * DfDg);
        float iDi = r3 * DfDg, iDf = r3 * DiDg, iDg = r3 * DiDf;
        float cn = fmaf(iDf, c0, iDi * fmaf(-2.f, iDg, 1.f));
        c0 = cn;
        float Do = 1.f + fast_exp2(fminf(-L1 * go, 20.f));
        float Dc = 1.f + fast_exp2(fminf(L2C * cn, 20.f));
        float r2 = fast_rcp(Do * Dc);
        float iDo = r2 * Dc, iDc = r2 * Do;
        _Float16 hq = (_Float16)(iDo * fmaf(-2.f, iDc, 1.f));

        // ---- write h to next LDS buffer, barrier, THEN issue global store
        h_s[buf ^ 1][(4 * quad) * HSTR + p] = hq;
        ap = ap_n;
        buf ^= 1;
        __syncthreads();

        Hg[0] = hq;              // drains at the NEXT barrier (~1 step later)
        Hg += OBS * MSG;
    }
}

// ---------------------------------------------------------------------------
// Kernel 4: attention via fp16 MFMA. R11 dbuf single-barrier structure, but
// __launch_bounds__(256,4): measured VGPR=84 fits the 128-VGPR cap, and
// LDS 4 x 34816 = 139 KB < 160 KB -> 16 waves/CU (2x R11) for latency hiding.
// Grid T*8; t = bid & 255 -> same-t blocks share an XCD for L2 reuse.
// ---------------------------------------------------------------------------
__global__ __launch_bounds__(256, 4)
void k_attn(const _Float16* __restrict__ qh, const float* __restrict__ cb,
            const _Float16* __restrict__ H16, const float* __restrict__ xnorm,
            float* __restrict__ outp) {
    const int t = blockIdx.x & 255;
    const int mq = blockIdx.x >> 8;               // 0..7
    const int tid = threadIdx.x;
    const int lane = tid & 63, wave = tid >> 6;
    const int l15 = lane & 15, quad = lane >> 4;
    const int m0 = mq * 128 + wave * 32;

    half8 afrag[2][4];
    floatx4 cbv[2];
#pragma unroll
    for (int mt = 0; mt < 2; ++mt) {
        const half8* qrow = (const half8*)(qh + (size_t)(m0 + mt * 16 + l15) * PED);
#pragma unroll
        for (int c = 0; c < 4; ++c) afrag[mt][c] = qrow[c * 4 + quad];
        cbv[mt] = *(const floatx4*)(cb + m0 + mt * 16 + quad * 4);
    }

    __shared__ half8 kbuf[2][64 * KSTR];          // 2 x 17408 B

    float outacc[8];
#pragma unroll
    for (int i = 0; i < 8; ++i) outacc[i] = 0.f;

    const half8* Ht = (const half8*)(H16 + (size_t)t * (OBS * MSG));
    const float* xb = xnorm + t * OBS;

    // stage chunk 0
    half8 pf[4];
#pragma unroll
    for (int i = 0; i < 4; ++i) pf[i] = Ht[i * 256 + tid];
#pragma unroll
    for (int i = 0; i < 4; ++i) {
        int f = i * 256 + tid;
        kbuf[0][(f >> 4) * KSTR + (f & 15)] = pf[i];
    }
    __syncthreads();

    for (int ch = 0; ch < 8; ++ch) {
        const int cur = ch & 1;
        // issue next-chunk loads (consumed only after the compute phase)
        if (ch < 7) {
            const half8* Hn = Ht + (ch + 1) * 1024;
#pragma unroll
            for (int i = 0; i < 4; ++i) pf[i] = Hn[i * 256 + tid];
        }

#pragma unroll
        for (int nt = 0; nt < 4; ++nt) {
            half8 bfrag[4];
#pragma unroll
            for (int c = 0; c < 4; ++c)
                bfrag[c] = kbuf[cur][(nt * 16 + l15) * KSTR + c * 4 + quad];

            floatx4 acc[2];
#pragma unroll
            for (int mt = 0; mt < 2; ++mt) {
                acc[mt] = cbv[mt];
#pragma unroll
                for (int c = 0; c < 4; ++c)
                    acc[mt] = __builtin_amdgcn_mfma_f32_16x16x32_f16(
                        afrag[mt][c], bfrag[c], acc[mt], 0, 0, 0);
            }

            const float sv = xb[ch * 64 + nt * 16 + l15];
#pragma unroll
            for (int mt = 0; mt < 2; ++mt) {
                float E0 = fast_exp2(fminf(acc[mt][0], 20.f));
                float E1 = fast_exp2(fminf(acc[mt][1], 20.f));
                float E2 = fast_exp2(fminf(acc[mt][2], 20.f));
                float E3 = fast_exp2(fminf(acc[mt][3], 20.f));
                float D0 = 1.f + E0, D1 = 1.f + E1, D2 = 1.f + E2, D3 = 1.f + E3;
                float m01 = D0 * D1, m23 = D2 * D3;
                float rp = fast_rcp(m01 * m23);
                float rA = rp * m23, rB = rp * m01;
                float i0 = rA * D1, i1 = rA * D0, i2 = rB * D3, i3 = rB * D2;
                outacc[mt * 4 + 0] = fmaf(fmaf(-2.f, i0, 1.f), sv, outacc[mt * 4 + 0]);
                outacc[mt * 4 + 1] = fmaf(fmaf(-2.f, i1, 1.f), sv, outacc[mt * 4 + 1]);
                outacc[mt * 4 + 2] = fmaf(fmaf(-2.f, i2, 1.f), sv, outacc[mt * 4 + 2]);
                outacc[mt * 4 + 3] = fmaf(fmaf(-2.f, i3, 1.f), sv, outacc[mt * 4 + 3]);
            }
        }

        // write prefetch into the other buffer, then single barrier
        if (ch < 7) {
#pragma unroll
            for (int i = 0; i < 4; ++i) {
                int f = i * 256 + tid;
                kbuf[cur ^ 1][(f >> 4) * KSTR + (f & 15)] = pf[i];
            }
        }
        __syncthreads();
    }

#pragma unroll
    for (int i = 0; i < 8; ++i) {
        float v = outacc[i];
        v += __shfl_xor(v, 1, 16);
        v += __shfl_xor(v, 2, 16);
        v += __shfl_xor(v, 4, 16);
        v += __shfl_xor(v, 8, 16);
        outacc[i] = v;
    }
    if (l15 == 0) {
        const int mbase = m0 + quad * 4;
#pragma unroll
        for (int mt = 0; mt < 2; ++mt)
#pragma unroll
            for (int r = 0; r < 4; ++r)
                outp[(size_t)t * HID + mbase + mt * 16 + r] = tanh_f(outacc[mt * 4 + r]);
    }
}

// ---------------------------------------------------------------------------
extern "C" void kernel_launch(void* const* d_in, const int* in_sizes, int n_in,
                              void* d_out, int out_size, void* d_ws, size_t ws_size,
                              hipStream_t stream) {
    const float* obs      = (const float*)d_in[0];   // (256,512)
    const float* prev_act = (const float*)d_in[1];   // (256,32)
    const float* in_shift = (const float*)d_in[2];   // (512,)
    const float* in_scale = (const float*)d_in[3];   // (512,)
    const float* pos_emb  = (const float*)d_in[4];   // (1024,128)
    const float* W_ih     = (const float*)d_in[5];   // (512,33)
    const float* b_ih     = (const float*)d_in[6];   // (512,)
    const float* W_hh     = (const float*)d_in[7];   // (512,128)
    const float* b_hh     = (const float*)d_in[8];   // (512,)
    const float* Wq       = (const float*)d_in[9];   // (128,128)
    const float* bq       = (const float*)d_in[10];  // (128,)
    const float* Wk       = (const float*)d_in[11];  // (128,128)
    const float* bk       = (const float*)d_in[12];  // (128,)
    float* outp = (float*)d_out;                     // (256,1024)

    // workspace layout (float offsets):
    //   xnorm:  0        (131072 f)
    //   apre_p: 131072   (131072 f)
    //   qh:     262144   (131072 halfs = 65536 f)
    //   cb:     327680   (1024 f)
    //   H16:    328704   (16777216 halfs)
    float* ws = (float*)d_ws;
    float* xnorm  = ws;
    float* apre_p = ws + 131072;
    _Float16* qh  = (_Float16*)(ws + 262144);
    float* cbuf   = ws + 327680;
    _Float16* H16 = (_Float16*)(ws + 328704);

    k_pre<<<T_STEPS, 256, 0, stream>>>(obs, prev_act, in_shift, in_scale,
                                       W_ih, b_ih, b_hh, xnorm, apre_p);
    k_qproj<<<HID, 128, 0, stream>>>(pos_emb, Wq, bq, Wk, bk, qh, cbuf);
    k_lstm<<<128, 512, 0, stream>>>(xnorm, apre_p, W_ih, W_hh, H16);
    k_attn<<<T_STEPS * 8, 256, 0, stream>>>(qh, cbuf, H16, xnorm, outp);
}